// Round 7
// baseline (278.289 us; speedup 1.0000x reference)
//
#include <hip/hip_runtime.h>
#include <hip/hip_bf16.h>
#include <stdint.h>

// Problem constants
#define B_    2
#define S_    2048
#define D_    1024
#define H_    16
#define NTOK  (B_ * S_)   // 4096

typedef __attribute__((ext_vector_type(8))) short bf16x8;
typedef __attribute__((ext_vector_type(4))) float f32x4;
typedef __attribute__((ext_vector_type(16))) float f32x16;
typedef __attribute__((ext_vector_type(2))) float float2v;
typedef __attribute__((ext_vector_type(2))) __bf16 bfv2;

// fp32 -> bf16 round-to-nearest-even (scalar)
static __device__ __forceinline__ unsigned short f2bf(float f) {
    unsigned int u = __float_as_uint(f);
    unsigned int r = (u + 0x7FFFu + ((u >> 16) & 1u)) >> 16;
    return (unsigned short)r;
}
// packed pair fp32 -> 2x bf16 (v_cvt_pk_bf16_f32, RNE)
static __device__ __forceinline__ unsigned int pkbf(float a, float b) {
    float2v fv = {a, b};
    bfv2 r = __builtin_convertvector(fv, bfv2);
    unsigned int u;
    __builtin_memcpy(&u, &r, 4);
    return u;
}

// async global->LDS, 16 B per lane; LDS dest = wave-uniform base + lane*16
using g_cu32 = __attribute__((address_space(1))) const unsigned int;
using l_u32  = __attribute__((address_space(3))) unsigned int;
static __device__ __forceinline__ void gld16(const void* g, void* l) {
    __builtin_amdgcn_global_load_lds((g_cu32*)g, (l_u32*)l, 16, 0, 0);
}

#define QN ((size_t)NTOK * D_)   // 4194304
#define WN ((size_t)D_ * D_)     // 1048576 = 1<<20

// ---------------------------------------------------------------------------
// prep: blocks [0,8192) = fp32->bf16 bulk convert (q,k,v + 4 weights);
//       blocks [8192,9216) = mask tile flags (flags[qt][kt] = any-zero in 64x64).
// ---------------------------------------------------------------------------
__global__ __launch_bounds__(256) void prep_kernel(
    const float* __restrict__ q, const float* __restrict__ k, const float* __restrict__ v,
    const float* __restrict__ Wq, const float* __restrict__ Wk,
    const float* __restrict__ Wv, const float* __restrict__ Wo,
    const int* __restrict__ mask,
    unsigned short* __restrict__ qb, unsigned short* __restrict__ kb,
    unsigned short* __restrict__ vb, unsigned short* __restrict__ wqb,
    unsigned short* __restrict__ wkb, unsigned short* __restrict__ wvb,
    unsigned short* __restrict__ wob, int* __restrict__ flags) {
    __shared__ int anyz;
    if (blockIdx.x < 8192) {
        size_t i = ((size_t)blockIdx.x * 256 + threadIdx.x) * 8;
        const float* s; unsigned short* d; size_t off;
        if (i < QN)          { s = q; d = qb; off = i; }
        else if (i < 2 * QN) { s = k; d = kb; off = i - QN; }
        else if (i < 3 * QN) { s = v; d = vb; off = i - 2 * QN; }
        else {
            size_t j = i - 3 * QN;
            int wi = (int)(j >> 20);
            s = (wi == 0) ? Wq : (wi == 1) ? Wk : (wi == 2) ? Wv : Wo;
            d = (wi == 0) ? wqb : (wi == 1) ? wkb : (wi == 2) ? wvb : wob;
            off = j & (WN - 1);
        }
        float4 a = *(const float4*)(s + off);
        float4 b = *(const float4*)(s + off + 4);
        uint4 pk;
        pk.x = pkbf(a.x, a.y); pk.y = pkbf(a.z, a.w);
        pk.z = pkbf(b.x, b.y); pk.w = pkbf(b.z, b.w);
        *(uint4*)(d + off) = pk;
    } else {
        if (threadIdx.x == 0) anyz = 0;
        __syncthreads();
        int bid2 = blockIdx.x - 8192;
        const int qt = bid2 >> 5, kt = bid2 & 31;
        int az = 0;
        for (int i = threadIdx.x; i < 64 * 64; i += 256) {
            int r = i >> 6, c = i & 63;
            az |= (mask[(size_t)(qt * 64 + r) * S_ + kt * 64 + c] == 0) ? 1 : 0;
        }
        if (az) atomicOr(&anyz, 1);
        __syncthreads();
        if (threadIdx.x == 0) flags[qt * 32 + kt] = anyz;
    }
}

// ---------------------------------------------------------------------------
// bf16 GEMM on 32x32x16 MFMA: C[M,N] = A[M,K] @ W[N,K]^T + bias, then *scale.
// BMT x 128 tile, BK=32, 256 thr = 4 waves (2x2 of 64x64).
// LDS region = 1 KB = [32 rows x 16 k], unit u (16B) = row (u&31), k-half
// (u>>5): async lane order == linear unit order == 32x32 A/B fragment order
// (lane m=lane&31, k = (lane>>5)*8 + j). Conflict-free lane-linear ds_read.
// C/D layout (m74/m101): col = lane&31, row = (reg&3) + 8*(reg>>2) + 4*(lane>>5).
// modes: 0 = fp32 out, 1 = bf16 out, 2 = bf16 Vt layout (Vt[(b*H+h)*64+d][s])
// ---------------------------------------------------------------------------
struct GemmArgs {
    const unsigned short* A[3];
    const unsigned short* W[3];
    const float* bias[3];
    void* C[3];
    int mode[3];
    float scale[3];
};

template<int BMT>
__global__ __launch_bounds__(256, 3) void gemm_async(GemmArgs ga) {
    constexpr int MI   = BMT / 64;   // 32-row acc tiles per wave (128->2, 64->1)
    constexpr int AREG = BMT / 16;   // A regions per K-iter
    constexpr int APW  = AREG / 4;   // A regions staged per wave
    const int z = blockIdx.z;
    const unsigned short* __restrict__ A = ga.A[z];
    const unsigned short* __restrict__ W = ga.W[z];
    const float* __restrict__ bias = ga.bias[z];
    void* C = ga.C[z];
    const int mode = ga.mode[z];
    const float scl = ga.scale[z];

    __shared__ unsigned short As[AREG * 512];
    __shared__ unsigned short Ws[8 * 512];

    const int t    = threadIdx.x;
    const int lane = t & 63;
    const int w    = t >> 6;
    const int ln31 = lane & 31;      // fragment row / C col
    const int lh   = lane >> 5;      // k-half / row offset 4*lh
    const int wrow = w >> 1, wcol = w & 1;
    const int m0 = blockIdx.x * BMT, n0 = blockIdx.y * 128;

    // staging: lane l loads (row = l&31, k-chunk = l>>5) of its region
    const unsigned short* gA[APW]; unsigned short* lA[APW];
#pragma unroll
    for (int i = 0; i < APW; ++i) {
        int r = w * APW + i, rg = r >> 1, ks = r & 1;
        gA[i] = A + (size_t)(m0 + rg * 32 + ln31) * D_ + ks * 16 + lh * 8;
        lA[i] = &As[r * 512];
    }
    const unsigned short* gW[2]; unsigned short* lW[2];
#pragma unroll
    for (int i = 0; i < 2; ++i) {
        int r = w * 2 + i, rg = r >> 1, ks = r & 1;
        gW[i] = W + (size_t)(n0 + rg * 32 + ln31) * D_ + ks * 16 + lh * 8;
        lW[i] = &Ws[r * 512];
    }

    f32x16 acc[MI][2];
#pragma unroll
    for (int i = 0; i < MI; ++i)
#pragma unroll
        for (int j = 0; j < 2; ++j) acc[i][j] = (f32x16)0.0f;

    for (int k0 = 0; k0 < D_ / 32; ++k0) {
#pragma unroll
        for (int i = 0; i < APW; ++i) { gld16(gA[i], lA[i]); gA[i] += 32; }
#pragma unroll
        for (int i = 0; i < 2; ++i) { gld16(gW[i], lW[i]); gW[i] += 32; }
        __syncthreads();

#pragma unroll
        for (int ks = 0; ks < 2; ++ks) {
            bf16x8 af[MI], bw[2];
#pragma unroll
            for (int mi = 0; mi < MI; ++mi)
                af[mi] = *(const bf16x8*)&As[((wrow * MI + mi) * 2 + ks) * 512 + lane * 8];
#pragma unroll
            for (int ni = 0; ni < 2; ++ni)
                bw[ni] = *(const bf16x8*)&Ws[((wcol * 2 + ni) * 2 + ks) * 512 + lane * 8];
#pragma unroll
            for (int mi = 0; mi < MI; ++mi)
#pragma unroll
                for (int ni = 0; ni < 2; ++ni)
                    acc[mi][ni] = __builtin_amdgcn_mfma_f32_32x32x16_bf16(
                        af[mi], bw[ni], acc[mi][ni], 0, 0, 0);
        }
        __syncthreads();
    }

    // epilogue
#pragma unroll
    for (int ni = 0; ni < 2; ++ni) {
        int col = n0 + wcol * 64 + ni * 32 + ln31;
        float bv = bias[col];
#pragma unroll
        for (int mi = 0; mi < MI; ++mi) {
            int rbase = m0 + wrow * (BMT / 2) + mi * 32 + 4 * lh;
            if (mode == 0) {
                float* Co = (float*)C;
#pragma unroll
                for (int rg = 0; rg < 4; ++rg)
#pragma unroll
                    for (int rr = 0; rr < 4; ++rr) {
                        int row = rbase + 8 * rg + rr;
                        Co[(size_t)row * D_ + col] = (acc[mi][ni][rg * 4 + rr] + bv) * scl;
                    }
            } else if (mode == 1) {
                unsigned short* Co = (unsigned short*)C;
#pragma unroll
                for (int rg = 0; rg < 4; ++rg)
#pragma unroll
                    for (int rr = 0; rr < 4; ++rr) {
                        int row = rbase + 8 * rg + rr;
                        Co[(size_t)row * D_ + col] = f2bf((acc[mi][ni][rg * 4 + rr] + bv) * scl);
                    }
            } else {
                // Vt[((b*H+h)*64+d)*S + s], 4 consecutive s per store
                unsigned short* Co = (unsigned short*)C;
                int hh = col >> 6, d = col & 63;
#pragma unroll
                for (int rg = 0; rg < 4; ++rg) {
                    int tok = rbase + 8 * rg;
                    int bb = tok >> 11, sb = tok & (S_ - 1);
                    uint2 pk;
                    pk.x = pkbf((acc[mi][ni][rg * 4 + 0] + bv) * scl,
                                (acc[mi][ni][rg * 4 + 1] + bv) * scl);
                    pk.y = pkbf((acc[mi][ni][rg * 4 + 2] + bv) * scl,
                                (acc[mi][ni][rg * 4 + 3] + bv) * scl);
                    *(uint2*)(Co + ((size_t)((bb * H_ + hh) * 64 + d)) * S_ + sb) = pk;
                }
            }
        }
    }
}

// ---------------------------------------------------------------------------
// MFMA flash attention v5 (unchanged from round 6): wave owns 32 q-rows,
// 128 q-rows/block, 64-key tiles, dbuf K/V, fixed-shift exp2 softmax.
// ---------------------------------------------------------------------------
__global__ __launch_bounds__(256, 2) void flash5(
    const unsigned short* __restrict__ Qb, const unsigned short* __restrict__ Kb,
    const unsigned short* __restrict__ Vtg, const int* __restrict__ mask,
    const int* __restrict__ flags, unsigned short* __restrict__ Xb) {
    __shared__ unsigned short Ks[2][4096];
    __shared__ unsigned short Vs[2][4096];
    __shared__ unsigned short Ps[8192];

    const int t    = threadIdx.x;
    const int lane = t & 63;
    const int w    = t >> 6;
    const int fr   = lane & 15;
    const int kq   = lane >> 4;
    const int qt = blockIdx.x, hd = blockIdx.y, b = blockIdx.z;
    const int q0 = qt * 128;
    const int qw = q0 + w * 32;
    const int swz = fr & 7;

    bf16x8 qf[2][2];
#pragma unroll
    for (int g = 0; g < 2; ++g) {
        const unsigned short* qp = Qb + (size_t)(b * S_ + qw + g * 16 + fr) * D_ + hd * 64;
        qf[g][0] = *(const bf16x8*)(qp + kq * 8);
        qf[g][1] = *(const bf16x8*)(qp + 32 + kq * 8);
    }

    int fl = (lane < 32) ? flags[(qw >> 6) * 32 + lane] : 0;
    unsigned int fmask = (unsigned int)__ballot(fl != 0);

    const unsigned short* kbase =
        Kb + (size_t)(b * S_ + w * 16 + fr) * D_ + hd * 64 + kq * 8;
    const unsigned short* vbase =
        Vtg + ((size_t)((b * H_ + hd) * 64 + w * 16 + fr)) * S_ + kq * 8;

#pragma unroll
    for (int j = 0; j < 2; ++j) {
        gld16(kbase + j * 32, (char*)&Ks[0][0] + w * 2048 + j * 1024);
        gld16(vbase + j * 32, (char*)&Vs[0][0] + w * 2048 + j * 1024);
    }

    f32x4 o[2][4];
#pragma unroll
    for (int g = 0; g < 2; ++g)
#pragma unroll
        for (int i = 0; i < 4; ++i) o[g][i] = (f32x4)0.0f;
    float l_i[2] = {0.0f, 0.0f};

    for (int kt = 0; kt < 32; ++kt) {
        const int cur = kt & 1;
        __syncthreads();
        if (kt < 31) {
#pragma unroll
            for (int j = 0; j < 2; ++j) {
                gld16(kbase + (size_t)(kt + 1) * 64 * D_ + j * 32,
                      (char*)&Ks[cur ^ 1][0] + w * 2048 + j * 1024);
                gld16(vbase + (size_t)(kt + 1) * 64 + j * 32,
                      (char*)&Vs[cur ^ 1][0] + w * 2048 + j * 1024);
            }
        }

        f32x4 st[2][4];
#pragma unroll
        for (int g = 0; g < 2; ++g)
#pragma unroll
            for (int mi = 0; mi < 4; ++mi) st[g][mi] = (f32x4)0.0f;
#pragma unroll
        for (int kk = 0; kk < 2; ++kk)
#pragma unroll
            for (int mi = 0; mi < 4; ++mi) {
                bf16x8 a = *(const bf16x8*)&Ks[cur][mi * 1024 + ((kk * 4 + kq) * 16 + fr) * 8];
                st[0][mi] = __builtin_amdgcn_mfma_f32_16x16x32_bf16(a, qf[0][kk], st[0][mi], 0, 0, 0);
                st[1][mi] = __builtin_amdgcn_mfma_f32_16x16x32_bf16(a, qf[1][kk], st[1][mi], 0, 0, 0);
            }

        if ((fmask >> kt) & 1u) {
#pragma unroll
            for (int g = 0; g < 2; ++g)
#pragma unroll
                for (int mi = 0; mi < 4; ++mi) {
                    int4 mv = *(const int4*)&mask[(size_t)(qw + g * 16 + fr) * S_ + kt * 64 + mi * 16 + kq * 4];
                    if (mv.x == 0) st[g][mi][0] = -3e8f;
                    if (mv.y == 0) st[g][mi][1] = -3e8f;
                    if (mv.z == 0) st[g][mi][2] = -3e8f;
                    if (mv.w == 0) st[g][mi][3] = -3e8f;
                }
        }

#pragma unroll
        for (int g = 0; g < 2; ++g)
#pragma unroll
            for (int mi = 0; mi < 4; ++mi) {
                float e0 = exp2f(st[g][mi][0]), e1 = exp2f(st[g][mi][1]);
                float e2 = exp2f(st[g][mi][2]), e3 = exp2f(st[g][mi][3]);
                l_i[g] += (e0 + e1) + (e2 + e3);
                uint2 pk;
                pk.x = pkbf(e0, e1);
                pk.y = pkbf(e2, e3);
                int chunk = mi * 2 + (kq >> 1);
                *(uint2*)&Ps[(w * 32 + g * 16 + fr) * 64 + ((chunk ^ swz) << 3) + ((kq & 1) << 2)] = pk;
            }

#pragma unroll
        for (int kk = 0; kk < 2; ++kk) {
            int c = kk * 4 + kq;
            bf16x8 pb0 = *(const bf16x8*)&Ps[(w * 32 + fr) * 64 + ((c ^ swz) << 3)];
            bf16x8 pb1 = *(const bf16x8*)&Ps[(w * 32 + 16 + fr) * 64 + ((c ^ swz) << 3)];
#pragma unroll
            for (int mi = 0; mi < 4; ++mi) {
                bf16x8 a = *(const bf16x8*)&Vs[cur][mi * 1024 + ((kk * 4 + kq) * 16 + fr) * 8];
                o[0][mi] = __builtin_amdgcn_mfma_f32_16x16x32_bf16(a, pb0, o[0][mi], 0, 0, 0);
                o[1][mi] = __builtin_amdgcn_mfma_f32_16x16x32_bf16(a, pb1, o[1][mi], 0, 0, 0);
            }
        }
    }

#pragma unroll
    for (int g = 0; g < 2; ++g) {
        float lg = l_i[g];
        lg += __shfl_xor(lg, 16, 64);
        lg += __shfl_xor(lg, 32, 64);
        float rl = 1.0f / lg;
#pragma unroll
        for (int mi = 0; mi < 4; ++mi) {
            uint2 pk;
            pk.x = pkbf(o[g][mi][0] * rl, o[g][mi][1] * rl);
            pk.y = pkbf(o[g][mi][2] * rl, o[g][mi][3] * rl);
            *(uint2*)(Xb + (size_t)(b * S_ + qw + g * 16 + fr) * D_ + hd * 64 + mi * 16 + kq * 4) = pk;
        }
    }
}

// ---------------------------------------------------------------------------
extern "C" void kernel_launch(void* const* d_in, const int* in_sizes, int n_in,
                              void* d_out, int out_size, void* d_ws, size_t ws_size,
                              hipStream_t stream) {
    const float* q    = (const float*)d_in[0];
    const float* k    = (const float*)d_in[1];
    const float* v    = (const float*)d_in[2];
    const int*   mask = (const int*)d_in[3];
    const float* Wq   = (const float*)d_in[4];
    const float* bq   = (const float*)d_in[5];
    const float* Wk   = (const float*)d_in[6];
    const float* bk   = (const float*)d_in[7];
    const float* Wv   = (const float*)d_in[8];
    const float* bv   = (const float*)d_in[9];
    const float* Wo   = (const float*)d_in[10];
    const float* bo   = (const float*)d_in[11];
    float* out = (float*)d_out;

    // workspace (shorts): qb kb vb | Qf Kf Vt | wqb wkb wvb wob | flags  (~59 MB)
    unsigned short* qb  = (unsigned short*)d_ws;
    unsigned short* kb  = qb + QN;
    unsigned short* vb  = kb + QN;
    unsigned short* Qf  = vb + QN;
    unsigned short* Kf  = Qf + QN;
    unsigned short* Vt  = Kf + QN;
    unsigned short* wqb = Vt + QN;
    unsigned short* wkb = wqb + WN;
    unsigned short* wvb = wkb + WN;
    unsigned short* wob = wvb + WN;
    int* flags = (int*)(wob + WN);

    const float SC = 0.18033688011112042f;  // (1/8) * log2(e)

    prep_kernel<<<9216, 256, 0, stream>>>(q, k, v, Wq, Wk, Wv, Wo, mask,
                                          qb, kb, vb, wqb, wkb, wvb, wob, flags);

    GemmArgs g1;
    g1.A[0] = qb;  g1.W[0] = wqb; g1.bias[0] = bq; g1.C[0] = Qf; g1.mode[0] = 1; g1.scale[0] = SC;
    g1.A[1] = kb;  g1.W[1] = wkb; g1.bias[1] = bk; g1.C[1] = Kf; g1.mode[1] = 1; g1.scale[1] = 1.0f;
    g1.A[2] = vb;  g1.W[2] = wvb; g1.bias[2] = bv; g1.C[2] = Vt; g1.mode[2] = 2; g1.scale[2] = 1.0f;
    gemm_async<128><<<dim3(NTOK / 128, D_ / 128, 3), 256, 0, stream>>>(g1);

    flash5<<<dim3(S_ / 128, H_, B_), 256, 0, stream>>>(Qf, Kf, Vt, mask, flags, Qf);

    GemmArgs g2;
    g2.A[0] = Qf; g2.W[0] = wob; g2.bias[0] = bo; g2.C[0] = out; g2.mode[0] = 0; g2.scale[0] = 1.0f;
    g2.A[1] = g2.A[2] = nullptr; g2.W[1] = g2.W[2] = nullptr;
    g2.bias[1] = g2.bias[2] = nullptr; g2.C[1] = g2.C[2] = nullptr;
    g2.mode[1] = g2.mode[2] = 0; g2.scale[1] = g2.scale[2] = 1.0f;
    gemm_async<64><<<dim3(NTOK / 64, D_ / 128, 1), 256, 0, stream>>>(g2);
}

// Round 8
// 277.653 us; speedup vs baseline: 1.0023x; 1.0023x over previous
//
#include <hip/hip_runtime.h>
#include <hip/hip_bf16.h>
#include <stdint.h>

// Problem constants
#define B_    2
#define S_    2048
#define D_    1024
#define H_    16
#define NTOK  (B_ * S_)   // 4096

typedef __attribute__((ext_vector_type(8))) short bf16x8;
typedef __attribute__((ext_vector_type(4))) float f32x4;
typedef __attribute__((ext_vector_type(16))) float f32x16;
typedef __attribute__((ext_vector_type(2))) float float2v;
typedef __attribute__((ext_vector_type(2))) __bf16 bfv2;

// fp32 -> bf16 round-to-nearest-even (scalar)
static __device__ __forceinline__ unsigned short f2bf(float f) {
    unsigned int u = __float_as_uint(f);
    unsigned int r = (u + 0x7FFFu + ((u >> 16) & 1u)) >> 16;
    return (unsigned short)r;
}
// packed pair fp32 -> 2x bf16 (v_cvt_pk_bf16_f32, RNE)
static __device__ __forceinline__ unsigned int pkbf(float a, float b) {
    float2v fv = {a, b};
    bfv2 r = __builtin_convertvector(fv, bfv2);
    unsigned int u;
    __builtin_memcpy(&u, &r, 4);
    return u;
}

// async global->LDS, 16 B per lane; LDS dest = wave-uniform base + lane*16
using g_cu32 = __attribute__((address_space(1))) const unsigned int;
using l_u32  = __attribute__((address_space(3))) unsigned int;
static __device__ __forceinline__ void gld16(const void* g, void* l) {
    __builtin_amdgcn_global_load_lds((g_cu32*)g, (l_u32*)l, 16, 0, 0);
}

#define QN ((size_t)NTOK * D_)   // 4194304
#define WN ((size_t)D_ * D_)     // 1048576 = 1<<20

// ---------------------------------------------------------------------------
// prep: blocks [0,8192) = fp32->bf16 bulk convert (q,k,v + 4 weights);
//       blocks [8192,9216) = mask tile flags (flags[qt][kt] = any-zero in 64x64).
// ---------------------------------------------------------------------------
__global__ __launch_bounds__(256) void prep_kernel(
    const float* __restrict__ q, const float* __restrict__ k, const float* __restrict__ v,
    const float* __restrict__ Wq, const float* __restrict__ Wk,
    const float* __restrict__ Wv, const float* __restrict__ Wo,
    const int* __restrict__ mask,
    unsigned short* __restrict__ qb, unsigned short* __restrict__ kb,
    unsigned short* __restrict__ vb, unsigned short* __restrict__ wqb,
    unsigned short* __restrict__ wkb, unsigned short* __restrict__ wvb,
    unsigned short* __restrict__ wob, int* __restrict__ flags) {
    __shared__ int anyz;
    if (blockIdx.x < 8192) {
        size_t i = ((size_t)blockIdx.x * 256 + threadIdx.x) * 8;
        const float* s; unsigned short* d; size_t off;
        if (i < QN)          { s = q; d = qb; off = i; }
        else if (i < 2 * QN) { s = k; d = kb; off = i - QN; }
        else if (i < 3 * QN) { s = v; d = vb; off = i - 2 * QN; }
        else {
            size_t j = i - 3 * QN;
            int wi = (int)(j >> 20);
            s = (wi == 0) ? Wq : (wi == 1) ? Wk : (wi == 2) ? Wv : Wo;
            d = (wi == 0) ? wqb : (wi == 1) ? wkb : (wi == 2) ? wvb : wob;
            off = j & (WN - 1);
        }
        float4 a = *(const float4*)(s + off);
        float4 b = *(const float4*)(s + off + 4);
        uint4 pk;
        pk.x = pkbf(a.x, a.y); pk.y = pkbf(a.z, a.w);
        pk.z = pkbf(b.x, b.y); pk.w = pkbf(b.z, b.w);
        *(uint4*)(d + off) = pk;
    } else {
        if (threadIdx.x == 0) anyz = 0;
        __syncthreads();
        int bid2 = blockIdx.x - 8192;
        const int qt = bid2 >> 5, kt = bid2 & 31;
        int az = 0;
        for (int i = threadIdx.x; i < 64 * 64; i += 256) {
            int r = i >> 6, c = i & 63;
            az |= (mask[(size_t)(qt * 64 + r) * S_ + kt * 64 + c] == 0) ? 1 : 0;
        }
        if (az) atomicOr(&anyz, 1);
        __syncthreads();
        if (threadIdx.x == 0) flags[qt * 32 + kt] = anyz;
    }
}

// ---------------------------------------------------------------------------
// bf16 GEMM on 32x32x16 MFMA, double-buffered single-barrier K-loop:
// C[M,N] = A[M,K] @ W[N,K]^T + bias, then *scale.
// BMT x 128 tile, BK=32, 256 thr = 4 waves (2x2 of 64x64).
// Per iter: barrier (tile k resident) -> prefetch k+1 into other buffer ->
// ds_read + MFMA on tile k. Staging latency hides behind a full tile of MFMA.
// LDS region = 1 KB = [32 rows x 16 k]; async lane order == linear unit order
// == 32x32 A/B fragment order. C/D layout (m74/m101):
// col = lane&31, row = (reg&3) + 8*(reg>>2) + 4*(lane>>5).
// modes: 0 = fp32 out, 1 = bf16 out, 2 = bf16 Vt layout (Vt[(b*H+h)*64+d][s])
// ---------------------------------------------------------------------------
struct GemmArgs {
    const unsigned short* A[3];
    const unsigned short* W[3];
    const float* bias[3];
    void* C[3];
    int mode[3];
    float scale[3];
};

template<int BMT>
__global__ __launch_bounds__(256, 3) void gemm_async(GemmArgs ga) {
    constexpr int MI   = BMT / 64;   // 32-row acc tiles per wave (128->2, 64->1)
    constexpr int AREG = BMT / 16;   // A regions per K-iter
    constexpr int APW  = AREG / 4;   // A regions staged per wave
    const int z = blockIdx.z;
    const unsigned short* __restrict__ A = ga.A[z];
    const unsigned short* __restrict__ W = ga.W[z];
    const float* __restrict__ bias = ga.bias[z];
    void* C = ga.C[z];
    const int mode = ga.mode[z];
    const float scl = ga.scale[z];

    __shared__ unsigned short As[2][AREG * 512];
    __shared__ unsigned short Ws[2][8 * 512];

    const int t    = threadIdx.x;
    const int lane = t & 63;
    const int w    = t >> 6;
    const int ln31 = lane & 31;      // fragment row / C col
    const int lh   = lane >> 5;      // k-half / row offset 4*lh
    const int wrow = w >> 1, wcol = w & 1;
    const int m0 = blockIdx.x * BMT, n0 = blockIdx.y * 128;

    // staging: lane l loads (row = l&31, k-chunk = l>>5) of its region
    const unsigned short* gA[APW]; int lAoff[APW];
#pragma unroll
    for (int i = 0; i < APW; ++i) {
        int r = w * APW + i, rg = r >> 1, ks = r & 1;
        gA[i] = A + (size_t)(m0 + rg * 32 + ln31) * D_ + ks * 16 + lh * 8;
        lAoff[i] = r * 512;
    }
    const unsigned short* gW[2]; int lWoff[2];
#pragma unroll
    for (int i = 0; i < 2; ++i) {
        int r = w * 2 + i, rg = r >> 1, ks = r & 1;
        gW[i] = W + (size_t)(n0 + rg * 32 + ln31) * D_ + ks * 16 + lh * 8;
        lWoff[i] = r * 512;
    }

    f32x16 acc[MI][2];
#pragma unroll
    for (int i = 0; i < MI; ++i)
#pragma unroll
        for (int j = 0; j < 2; ++j) acc[i][j] = (f32x16)0.0f;

    // prefetch K-iter 0 into buffer 0
#pragma unroll
    for (int i = 0; i < APW; ++i) gld16(gA[i], &As[0][lAoff[i]]);
#pragma unroll
    for (int i = 0; i < 2; ++i) gld16(gW[i], &Ws[0][lWoff[i]]);

    constexpr int NIT = D_ / 32;
    for (int k0 = 0; k0 < NIT; ++k0) {
        const int cur = k0 & 1;
        __syncthreads();   // tile k0 resident; buffer cur^1 free
        if (k0 + 1 < NIT) {
            const size_t koff = (size_t)(k0 + 1) * 32;
#pragma unroll
            for (int i = 0; i < APW; ++i) gld16(gA[i] + koff, &As[cur ^ 1][lAoff[i]]);
#pragma unroll
            for (int i = 0; i < 2; ++i) gld16(gW[i] + koff, &Ws[cur ^ 1][lWoff[i]]);
        }

#pragma unroll
        for (int ks = 0; ks < 2; ++ks) {
            bf16x8 af[MI], bw[2];
#pragma unroll
            for (int mi = 0; mi < MI; ++mi)
                af[mi] = *(const bf16x8*)&As[cur][((wrow * MI + mi) * 2 + ks) * 512 + lane * 8];
#pragma unroll
            for (int ni = 0; ni < 2; ++ni)
                bw[ni] = *(const bf16x8*)&Ws[cur][((wcol * 2 + ni) * 2 + ks) * 512 + lane * 8];
#pragma unroll
            for (int mi = 0; mi < MI; ++mi)
#pragma unroll
                for (int ni = 0; ni < 2; ++ni)
                    acc[mi][ni] = __builtin_amdgcn_mfma_f32_32x32x16_bf16(
                        af[mi], bw[ni], acc[mi][ni], 0, 0, 0);
        }
    }

    // epilogue
#pragma unroll
    for (int ni = 0; ni < 2; ++ni) {
        int col = n0 + wcol * 64 + ni * 32 + ln31;
        float bv = bias[col];
#pragma unroll
        for (int mi = 0; mi < MI; ++mi) {
            int rbase = m0 + wrow * (BMT / 2) + mi * 32 + 4 * lh;
            if (mode == 0) {
                float* Co = (float*)C;
#pragma unroll
                for (int rg = 0; rg < 4; ++rg)
#pragma unroll
                    for (int rr = 0; rr < 4; ++rr) {
                        int row = rbase + 8 * rg + rr;
                        Co[(size_t)row * D_ + col] = (acc[mi][ni][rg * 4 + rr] + bv) * scl;
                    }
            } else if (mode == 1) {
                unsigned short* Co = (unsigned short*)C;
#pragma unroll
                for (int rg = 0; rg < 4; ++rg)
#pragma unroll
                    for (int rr = 0; rr < 4; ++rr) {
                        int row = rbase + 8 * rg + rr;
                        Co[(size_t)row * D_ + col] = f2bf((acc[mi][ni][rg * 4 + rr] + bv) * scl);
                    }
            } else {
                // Vt[((b*H+h)*64+d)*S + s], 4 consecutive s per store
                unsigned short* Co = (unsigned short*)C;
                int hh = col >> 6, d = col & 63;
#pragma unroll
                for (int rg = 0; rg < 4; ++rg) {
                    int tok = rbase + 8 * rg;
                    int bb = tok >> 11, sb = tok & (S_ - 1);
                    uint2 pk;
                    pk.x = pkbf((acc[mi][ni][rg * 4 + 0] + bv) * scl,
                                (acc[mi][ni][rg * 4 + 1] + bv) * scl);
                    pk.y = pkbf((acc[mi][ni][rg * 4 + 2] + bv) * scl,
                                (acc[mi][ni][rg * 4 + 3] + bv) * scl);
                    *(uint2*)(Co + ((size_t)((bb * H_ + hh) * 64 + d)) * S_ + sb) = pk;
                }
            }
        }
    }
}

// ---------------------------------------------------------------------------
// MFMA flash attention v5 (unchanged): wave owns 32 q-rows, 128 q-rows/block,
// 64-key tiles, dbuf K/V, fixed-shift exp2 softmax (Q pre-scaled).
// ---------------------------------------------------------------------------
__global__ __launch_bounds__(256, 2) void flash5(
    const unsigned short* __restrict__ Qb, const unsigned short* __restrict__ Kb,
    const unsigned short* __restrict__ Vtg, const int* __restrict__ mask,
    const int* __restrict__ flags, unsigned short* __restrict__ Xb) {
    __shared__ unsigned short Ks[2][4096];
    __shared__ unsigned short Vs[2][4096];
    __shared__ unsigned short Ps[8192];

    const int t    = threadIdx.x;
    const int lane = t & 63;
    const int w    = t >> 6;
    const int fr   = lane & 15;
    const int kq   = lane >> 4;
    const int qt = blockIdx.x, hd = blockIdx.y, b = blockIdx.z;
    const int q0 = qt * 128;
    const int qw = q0 + w * 32;
    const int swz = fr & 7;

    bf16x8 qf[2][2];
#pragma unroll
    for (int g = 0; g < 2; ++g) {
        const unsigned short* qp = Qb + (size_t)(b * S_ + qw + g * 16 + fr) * D_ + hd * 64;
        qf[g][0] = *(const bf16x8*)(qp + kq * 8);
        qf[g][1] = *(const bf16x8*)(qp + 32 + kq * 8);
    }

    int fl = (lane < 32) ? flags[(qw >> 6) * 32 + lane] : 0;
    unsigned int fmask = (unsigned int)__ballot(fl != 0);

    const unsigned short* kbase =
        Kb + (size_t)(b * S_ + w * 16 + fr) * D_ + hd * 64 + kq * 8;
    const unsigned short* vbase =
        Vtg + ((size_t)((b * H_ + hd) * 64 + w * 16 + fr)) * S_ + kq * 8;

#pragma unroll
    for (int j = 0; j < 2; ++j) {
        gld16(kbase + j * 32, (char*)&Ks[0][0] + w * 2048 + j * 1024);
        gld16(vbase + j * 32, (char*)&Vs[0][0] + w * 2048 + j * 1024);
    }

    f32x4 o[2][4];
#pragma unroll
    for (int g = 0; g < 2; ++g)
#pragma unroll
        for (int i = 0; i < 4; ++i) o[g][i] = (f32x4)0.0f;
    float l_i[2] = {0.0f, 0.0f};

    for (int kt = 0; kt < 32; ++kt) {
        const int cur = kt & 1;
        __syncthreads();
        if (kt < 31) {
#pragma unroll
            for (int j = 0; j < 2; ++j) {
                gld16(kbase + (size_t)(kt + 1) * 64 * D_ + j * 32,
                      (char*)&Ks[cur ^ 1][0] + w * 2048 + j * 1024);
                gld16(vbase + (size_t)(kt + 1) * 64 + j * 32,
                      (char*)&Vs[cur ^ 1][0] + w * 2048 + j * 1024);
            }
        }

        f32x4 st[2][4];
#pragma unroll
        for (int g = 0; g < 2; ++g)
#pragma unroll
            for (int mi = 0; mi < 4; ++mi) st[g][mi] = (f32x4)0.0f;
#pragma unroll
        for (int kk = 0; kk < 2; ++kk)
#pragma unroll
            for (int mi = 0; mi < 4; ++mi) {
                bf16x8 a = *(const bf16x8*)&Ks[cur][mi * 1024 + ((kk * 4 + kq) * 16 + fr) * 8];
                st[0][mi] = __builtin_amdgcn_mfma_f32_16x16x32_bf16(a, qf[0][kk], st[0][mi], 0, 0, 0);
                st[1][mi] = __builtin_amdgcn_mfma_f32_16x16x32_bf16(a, qf[1][kk], st[1][mi], 0, 0, 0);
            }

        if ((fmask >> kt) & 1u) {
#pragma unroll
            for (int g = 0; g < 2; ++g)
#pragma unroll
                for (int mi = 0; mi < 4; ++mi) {
                    int4 mv = *(const int4*)&mask[(size_t)(qw + g * 16 + fr) * S_ + kt * 64 + mi * 16 + kq * 4];
                    if (mv.x == 0) st[g][mi][0] = -3e8f;
                    if (mv.y == 0) st[g][mi][1] = -3e8f;
                    if (mv.z == 0) st[g][mi][2] = -3e8f;
                    if (mv.w == 0) st[g][mi][3] = -3e8f;
                }
        }

#pragma unroll
        for (int g = 0; g < 2; ++g)
#pragma unroll
            for (int mi = 0; mi < 4; ++mi) {
                float e0 = exp2f(st[g][mi][0]), e1 = exp2f(st[g][mi][1]);
                float e2 = exp2f(st[g][mi][2]), e3 = exp2f(st[g][mi][3]);
                l_i[g] += (e0 + e1) + (e2 + e3);
                uint2 pk;
                pk.x = pkbf(e0, e1);
                pk.y = pkbf(e2, e3);
                int chunk = mi * 2 + (kq >> 1);
                *(uint2*)&Ps[(w * 32 + g * 16 + fr) * 64 + ((chunk ^ swz) << 3) + ((kq & 1) << 2)] = pk;
            }

#pragma unroll
        for (int kk = 0; kk < 2; ++kk) {
            int c = kk * 4 + kq;
            bf16x8 pb0 = *(const bf16x8*)&Ps[(w * 32 + fr) * 64 + ((c ^ swz) << 3)];
            bf16x8 pb1 = *(const bf16x8*)&Ps[(w * 32 + 16 + fr) * 64 + ((c ^ swz) << 3)];
#pragma unroll
            for (int mi = 0; mi < 4; ++mi) {
                bf16x8 a = *(const bf16x8*)&Vs[cur][mi * 1024 + ((kk * 4 + kq) * 16 + fr) * 8];
                o[0][mi] = __builtin_amdgcn_mfma_f32_16x16x32_bf16(a, pb0, o[0][mi], 0, 0, 0);
                o[1][mi] = __builtin_amdgcn_mfma_f32_16x16x32_bf16(a, pb1, o[1][mi], 0, 0, 0);
            }
        }
    }

#pragma unroll
    for (int g = 0; g < 2; ++g) {
        float lg = l_i[g];
        lg += __shfl_xor(lg, 16, 64);
        lg += __shfl_xor(lg, 32, 64);
        float rl = 1.0f / lg;
#pragma unroll
        for (int mi = 0; mi < 4; ++mi) {
            uint2 pk;
            pk.x = pkbf(o[g][mi][0] * rl, o[g][mi][1] * rl);
            pk.y = pkbf(o[g][mi][2] * rl, o[g][mi][3] * rl);
            *(uint2*)(Xb + (size_t)(b * S_ + qw + g * 16 + fr) * D_ + hd * 64 + mi * 16 + kq * 4) = pk;
        }
    }
}

// ---------------------------------------------------------------------------
extern "C" void kernel_launch(void* const* d_in, const int* in_sizes, int n_in,
                              void* d_out, int out_size, void* d_ws, size_t ws_size,
                              hipStream_t stream) {
    const float* q    = (const float*)d_in[0];
    const float* k    = (const float*)d_in[1];
    const float* v    = (const float*)d_in[2];
    const int*   mask = (const int*)d_in[3];
    const float* Wq   = (const float*)d_in[4];
    const float* bq   = (const float*)d_in[5];
    const float* Wk   = (const float*)d_in[6];
    const float* bk   = (const float*)d_in[7];
    const float* Wv   = (const float*)d_in[8];
    const float* bv   = (const float*)d_in[9];
    const float* Wo   = (const float*)d_in[10];
    const float* bo   = (const float*)d_in[11];
    float* out = (float*)d_out;

    // workspace (shorts): qb kb vb | Qf Kf Vt | wqb wkb wvb wob | flags  (~59 MB)
    unsigned short* qb  = (unsigned short*)d_ws;
    unsigned short* kb  = qb + QN;
    unsigned short* vb  = kb + QN;
    unsigned short* Qf  = vb + QN;
    unsigned short* Kf  = Qf + QN;
    unsigned short* Vt  = Kf + QN;
    unsigned short* wqb = Vt + QN;
    unsigned short* wkb = wqb + WN;
    unsigned short* wvb = wkb + WN;
    unsigned short* wob = wvb + WN;
    int* flags = (int*)(wob + WN);

    const float SC = 0.18033688011112042f;  // (1/8) * log2(e)

    prep_kernel<<<9216, 256, 0, stream>>>(q, k, v, Wq, Wk, Wv, Wo, mask,
                                          qb, kb, vb, wqb, wkb, wvb, wob, flags);

    GemmArgs g1;
    g1.A[0] = qb;  g1.W[0] = wqb; g1.bias[0] = bq; g1.C[0] = Qf; g1.mode[0] = 1; g1.scale[0] = SC;
    g1.A[1] = kb;  g1.W[1] = wkb; g1.bias[1] = bk; g1.C[1] = Kf; g1.mode[1] = 1; g1.scale[1] = 1.0f;
    g1.A[2] = vb;  g1.W[2] = wvb; g1.bias[2] = bv; g1.C[2] = Vt; g1.mode[2] = 2; g1.scale[2] = 1.0f;
    gemm_async<128><<<dim3(NTOK / 128, D_ / 128, 3), 256, 0, stream>>>(g1);

    flash5<<<dim3(S_ / 128, H_, B_), 256, 0, stream>>>(Qf, Kf, Vt, mask, flags, Qf);

    GemmArgs g2;
    g2.A[0] = Qf; g2.W[0] = wob; g2.bias[0] = bo; g2.C[0] = out; g2.mode[0] = 0; g2.scale[0] = 1.0f;
    g2.A[1] = g2.A[2] = nullptr; g2.W[1] = g2.W[2] = nullptr;
    g2.bias[1] = g2.bias[2] = nullptr; g2.C[1] = g2.C[2] = nullptr;
    g2.mode[1] = g2.mode[2] = 0; g2.scale[1] = g2.scale[2] = 1.0f;
    gemm_async<64><<<dim3(NTOK / 64, D_ / 128, 1), 256, 0, stream>>>(g2);
}